// Round 9
// baseline (178.179 us; speedup 1.0000x reference)
//
#include <hip/hip_runtime.h>
#include <hip/hip_bf16.h>

// 2-layer GCN on MI355X, round 9.
// r8 lessons: (1) k_l2 is bound by the serial slot->aggS dependent-load chain
// (VALU cut did nothing); fix = 2 rows/wave with interleaved edge walks for
// 2x memory-level parallelism. (2) k_fill atomic traffic is irreducible per
// edge; test latency- vs throughput-bound by doubling blocks (2 edges/thr).
//   memset cursor -> k_fill(+w2t) -> k_agg (aggS,d5) -> k_l2 (tile+MFMA)

constexpr int NN = 50000;
constexpr int NE = 800000;
constexpr int CAP = 64;        // in-deg ~ Poisson(16); P(any node >= 65) ~ 1e-15
constexpr int NB_TILE = 3128;  // ceil(50000/16)

typedef __attribute__((ext_vector_type(8))) short bf16x8;
typedef __attribute__((ext_vector_type(4))) float f32x4;

#define ALIGN_UP(x, a) (((x) + (a) - 1) / (a) * (a))

struct Args {
    const float4* x;
    const int2* src2;
    const int2* dst2;
    const float* W1;
    const float* b1;
    const float* W2;
    const float* b2;
    int* cursor;
    unsigned short* slots;   // src ids fit in 16 bits (NN < 65536)
    float4* aggS;            // (A_hat x)[n] * dinv[n]
    float* d5;               // dinv[n]
    __hip_bfloat16* w2t;     // w2t[c][k] = bf16(W2[k][c])
    float* out;
};

// Bucket-CSR fill: 1 int atomic per edge, 2B slot store. 2 edges/thread ->
// 1563 blocks (6/CU) for more outstanding atomics. Block 0 builds w2t.
__global__ __launch_bounds__(256) void k_fill(Args a) {
    int i = blockIdx.x * 256 + threadIdx.x;
    if (i < NE / 2) {
        int2 s = a.src2[i];
        int2 d = a.dst2[i];
        int p0 = atomicAdd(&a.cursor[d.x], 1);
        a.slots[d.x * CAP + p0] = (unsigned short)s.x;
        int p1 = atomicAdd(&a.cursor[d.y], 1);
        a.slots[d.y * CAP + p1] = (unsigned short)s.y;
    }
    if (blockIdx.x == 0) {
        for (int idx = threadIdx.x; idx < 4096; idx += 256) {
            int c = idx >> 6, k = idx & 63;
            a.w2t[idx] = __float2bfloat16(a.W2[k * 64 + c]);
        }
    }
}

// aggS[n] = (x[n]*di^2 + di * sum_s x[s]*dinv[s]) * di;  d5[n] = di.
// 16 lanes per node, 4 nodes per wave.
__global__ __launch_bounds__(256) void k_agg(Args a) {
    int tid = threadIdx.x;
    int t = tid & 15;
    int node = (blockIdx.x * 256 + tid) >> 4;  // grid sized exactly: NN/16 blocks
    int deg = a.cursor[node];
    float ax = 0.f, ay = 0.f, az = 0.f, aw = 0.f;
    const unsigned short* sl = a.slots + node * CAP;
    for (int j = t; j < deg; j += 16) {
        int s = sl[j];
        float4 xs = a.x[s];
        float w = rsqrtf((float)(a.cursor[s] + 1));
        ax = fmaf(xs.x, w, ax);
        ay = fmaf(xs.y, w, ay);
        az = fmaf(xs.z, w, az);
        aw = fmaf(xs.w, w, aw);
    }
#pragma unroll
    for (int o = 8; o >= 1; o >>= 1) {
        ax += __shfl_xor(ax, o);
        ay += __shfl_xor(ay, o);
        az += __shfl_xor(az, o);
        aw += __shfl_xor(aw, o);
    }
    if (t == 0) {
        float di = rsqrtf((float)(deg + 1));
        float di2 = di * di, di3 = di2 * di;
        float4 xs = a.x[node];
        a.aggS[node] = make_float4(fmaf(ax, di2, xs.x * di3),
                                   fmaf(ay, di2, xs.y * di3),
                                   fmaf(az, di2, xs.z * di3),
                                   fmaf(aw, di2, xs.w * di3));
        a.d5[node] = di;
    }
}

// Per-edge message for channel `lane`: m = aggS[s].W1col + b1c*d5[s];
// contribution = relu(m). (relu(h)*dinv == relu(h*dinv), dinv>0.)
#define EDGE4(SL, J, ACC)                                                       \
    {                                                                           \
        ushort4 s4 = *reinterpret_cast<const ushort4*>((SL) + (J));             \
        float4 e0 = a.aggS[s4.x], e1 = a.aggS[s4.y];                            \
        float4 e2 = a.aggS[s4.z], e3 = a.aggS[s4.w];                            \
        float q0 = a.d5[s4.x], q1 = a.d5[s4.y];                                 \
        float q2 = a.d5[s4.z], q3 = a.d5[s4.w];                                 \
        float m0 = fmaf(e0.x, w0, fmaf(e0.y, w1, fmaf(e0.z, w2, fmaf(e0.w, w3, b1c * q0)))); \
        float m1 = fmaf(e1.x, w0, fmaf(e1.y, w1, fmaf(e1.z, w2, fmaf(e1.w, w3, b1c * q1)))); \
        float m2 = fmaf(e2.x, w0, fmaf(e2.y, w1, fmaf(e2.z, w2, fmaf(e2.w, w3, b1c * q2)))); \
        float m3 = fmaf(e3.x, w0, fmaf(e3.y, w1, fmaf(e3.z, w2, fmaf(e3.w, w3, b1c * q3)))); \
        (ACC) += fmaxf(m0, 0.f);                                                \
        (ACC) += fmaxf(m1, 0.f);                                                \
        (ACC) += fmaxf(m2, 0.f);                                                \
        (ACC) += fmaxf(m3, 0.f);                                                \
    }

#define EDGE1(SL, J, ACC)                                                       \
    {                                                                           \
        int s0 = (SL)[(J)];                                                     \
        float4 e0 = a.aggS[s0];                                                 \
        float m0 = fmaf(e0.x, w0, fmaf(e0.y, w1,                                \
                    fmaf(e0.z, w2, fmaf(e0.w, w3, b1c * a.d5[s0]))));           \
        (ACC) += fmaxf(m0, 0.f);                                                \
    }

// Layer 2 fused; 512-thread block = 8 waves per 16-node tile; wave w owns
// rows 2w, 2w+1 with INTERLEAVED edge walks (2 slot + 8 aggS + 8 d5 loads in
// flight). Rows -> bf16 LDS tile; waves 0-3 run the 4 MFMA col-tiles.
__global__ __launch_bounds__(512) void k_l2(Args a) {
    __shared__ __hip_bfloat16 tile[16][72];
    int tid = threadIdx.x;
    int wv = tid >> 6, lane = tid & 63;
    float w0 = a.W1[lane], w1 = a.W1[64 + lane];
    float w2 = a.W1[128 + lane], w3 = a.W1[192 + lane];
    float b1c = a.b1[lane];
    int base = blockIdx.x * 16;

    int nA = base + wv * 2, nB = nA + 1;
    bool vA = nA < NN, vB = nB < NN;
    float accA = 0.f, accB = 0.f;
    int degA = 0, degB = 0;
    const unsigned short* slA = a.slots + nA * CAP;
    const unsigned short* slB = a.slots + nB * CAP;
    if (vA) {
        degA = a.cursor[nA];
        float4 as = a.aggS[nA];
        float ms = fmaf(as.x, w0, fmaf(as.y, w1,
                    fmaf(as.z, w2, fmaf(as.w, w3, b1c * a.d5[nA]))));
        accA = fmaxf(ms, 0.f);
    }
    if (vB) {
        degB = a.cursor[nB];
        float4 bs = a.aggS[nB];
        float ms = fmaf(bs.x, w0, fmaf(bs.y, w1,
                    fmaf(bs.z, w2, fmaf(bs.w, w3, b1c * a.d5[nB]))));
        accB = fmaxf(ms, 0.f);
    }

    int jA = 0, jB = 0;
    // Joint loop: both rows advance together -> 2x loads in flight.
    while (jA + 3 < degA && jB + 3 < degB) {
        EDGE4(slA, jA, accA);
        EDGE4(slB, jB, accB);
        jA += 4;
        jB += 4;
    }
    // Drain row A.
    for (; jA + 3 < degA; jA += 4) EDGE4(slA, jA, accA);
    for (; jA < degA; ++jA) EDGE1(slA, jA, accA);
    // Drain row B.
    for (; jB + 3 < degB; jB += 4) EDGE4(slB, jB, accB);
    for (; jB < degB; ++jB) EDGE1(slB, jB, accB);

    if (vA) accA *= a.d5[nA];
    if (vB) accB *= a.d5[nB];
    tile[wv * 2][lane] = __float2bfloat16(accA);
    tile[wv * 2 + 1][lane] = __float2bfloat16(accB);
    __syncthreads();

    // MFMA epilogue (fragment layouts verified end-to-end r3-r5); waves 0-3.
    if (wv < 4) {
        int g = lane >> 4, c16 = lane & 15;
        int col = wv * 16 + c16;
        bf16x8 a0 = *reinterpret_cast<const bf16x8*>(&tile[c16][g * 8]);
        bf16x8 a1 = *reinterpret_cast<const bf16x8*>(&tile[c16][32 + g * 8]);
        bf16x8 bb0 = *reinterpret_cast<const bf16x8*>(a.w2t + col * 64 + g * 8);
        bf16x8 bb1 = *reinterpret_cast<const bf16x8*>(a.w2t + col * 64 + 32 + g * 8);
        f32x4 acc4 = {0.f, 0.f, 0.f, 0.f};
        acc4 = __builtin_amdgcn_mfma_f32_16x16x32_bf16(a0, bb0, acc4, 0, 0, 0);
        acc4 = __builtin_amdgcn_mfma_f32_16x16x32_bf16(a1, bb1, acc4, 0, 0, 0);
        float b2v = a.b2[col];
#pragma unroll
        for (int rg = 0; rg < 4; ++rg) {
            int node = base + g * 4 + rg;
            if (node < NN) a.out[node * 64 + col] = fmaxf(acc4[rg] + b2v, 0.f);
        }
    }
}

extern "C" void kernel_launch(void* const* d_in, const int* in_sizes, int n_in,
                              void* d_out, int out_size, void* d_ws, size_t ws_size,
                              hipStream_t stream) {
    const float* x  = (const float*)d_in[0];
    const int*   ei = (const int*)d_in[1];  // [2, NE]: src row then dst row
    const float* W1 = (const float*)d_in[2];
    const float* b1 = (const float*)d_in[3];
    const float* W2 = (const float*)d_in[4];
    const float* b2 = (const float*)d_in[5];

    char* w = (char*)d_ws;
    auto take = [&](size_t bytes) { char* p = w; w += ALIGN_UP(bytes, 256); return p; };
    int*            cursor = (int*)           take((size_t)NN * 4);
    unsigned short* slots  = (unsigned short*)take((size_t)NN * CAP * 2);  // 6.4 MB
    float*          aggS   = (float*)         take((size_t)NN * 16);
    float*          d5     = (float*)         take((size_t)NN * 4);
    __hip_bfloat16* w2t    = (__hip_bfloat16*)take(4096 * 2);

    Args args;
    args.x = (const float4*)x;
    args.src2 = (const int2*)ei;
    args.dst2 = (const int2*)(ei + NE);
    args.W1 = W1; args.b1 = b1; args.W2 = W2; args.b2 = b2;
    args.cursor = cursor; args.slots = slots;
    args.aggS = (float4*)aggS; args.d5 = d5; args.w2t = w2t;
    args.out = (float*)d_out;

    hipMemsetAsync(cursor, 0, (size_t)NN * 4, stream);
    k_fill<<<(NE / 2 + 255) / 256, 256, 0, stream>>>(args);  // 1563 blocks
    k_agg<<<NN / 16, 256, 0, stream>>>(args);                // 3125 blocks
    k_l2<<<NB_TILE, 512, 0, stream>>>(args);                 // 3128 blocks
}

// Round 10
// 151.238 us; speedup vs baseline: 1.1781x; 1.1781x over previous
//
#include <hip/hip_runtime.h>
#include <hip/hip_bf16.h>

// 2-layer GCN on MI355X, round 10.
// r9 lessons: (1) k_fill is at the scattered-atomic THROUGHPUT ceiling
// (occupancy 27->49% changed nothing) -- parked. (2) k_l2's bottleneck is the
// serial wave-uniform broadcast-load chain (slot->aggS, ~5 deep per row).
// Fix: lane-parallel gather (64 lanes stage a whole row's edge data in ONE
// chain of depth 2) into LDS, then the per-channel sweep replays from LDS.
//   memset cursor -> k_fill(+w2t) -> k_agg (aggS,d5) -> k_l2 (stage+MFMA)

constexpr int NN = 50000;
constexpr int NE = 800000;
constexpr int CAP = 64;        // in-deg ~ Poisson(16); P(any node >= 65) ~ 1e-15
constexpr int NB_TILE = 3128;  // ceil(50000/16)

typedef __attribute__((ext_vector_type(8))) short bf16x8;
typedef __attribute__((ext_vector_type(4))) float f32x4;

#define ALIGN_UP(x, a) (((x) + (a) - 1) / (a) * (a))

struct Args {
    const float4* x;
    const int2* src2;
    const int2* dst2;
    const float* W1;
    const float* b1;
    const float* W2;
    const float* b2;
    int* cursor;
    unsigned short* slots;   // src ids fit in 16 bits (NN < 65536)
    float4* aggS;            // (A_hat x)[n] * dinv[n]
    float* d5;               // dinv[n]
    __hip_bfloat16* w2t;     // w2t[c][k] = bf16(W2[k][c])
    float* out;
};

// Bucket-CSR fill: 1 int atomic per edge, 2B slot store. Block 0 builds w2t.
__global__ __launch_bounds__(256) void k_fill(Args a) {
    int i = blockIdx.x * 256 + threadIdx.x;
    if (i < NE / 2) {
        int2 s = a.src2[i];
        int2 d = a.dst2[i];
        int p0 = atomicAdd(&a.cursor[d.x], 1);
        a.slots[d.x * CAP + p0] = (unsigned short)s.x;
        int p1 = atomicAdd(&a.cursor[d.y], 1);
        a.slots[d.y * CAP + p1] = (unsigned short)s.y;
    }
    if (blockIdx.x == 0) {
        for (int idx = threadIdx.x; idx < 4096; idx += 256) {
            int c = idx >> 6, k = idx & 63;
            a.w2t[idx] = __float2bfloat16(a.W2[k * 64 + c]);
        }
    }
}

// aggS[n] = (x[n]*di^2 + di * sum_s x[s]*dinv[s]) * di;  d5[n] = di.
// 16 lanes per node, 4 nodes per wave.
__global__ __launch_bounds__(256) void k_agg(Args a) {
    int tid = threadIdx.x;
    int t = tid & 15;
    int node = (blockIdx.x * 256 + tid) >> 4;  // grid exact: NN/16 blocks
    int deg = a.cursor[node];
    float ax = 0.f, ay = 0.f, az = 0.f, aw = 0.f;
    const unsigned short* sl = a.slots + node * CAP;
    for (int j = t; j < deg; j += 16) {
        int s = sl[j];
        float4 xs = a.x[s];
        float w = rsqrtf((float)(a.cursor[s] + 1));
        ax = fmaf(xs.x, w, ax);
        ay = fmaf(xs.y, w, ay);
        az = fmaf(xs.z, w, az);
        aw = fmaf(xs.w, w, aw);
    }
#pragma unroll
    for (int o = 8; o >= 1; o >>= 1) {
        ax += __shfl_xor(ax, o);
        ay += __shfl_xor(ay, o);
        az += __shfl_xor(az, o);
        aw += __shfl_xor(aw, o);
    }
    if (t == 0) {
        float di = rsqrtf((float)(deg + 1));
        float di2 = di * di, di3 = di2 * di;
        float4 xs = a.x[node];
        a.aggS[node] = make_float4(fmaf(ax, di2, xs.x * di3),
                                   fmaf(ay, di2, xs.y * di3),
                                   fmaf(az, di2, xs.z * di3),
                                   fmaf(aw, di2, xs.w * di3));
        a.d5[node] = di;
    }
}

// Layer 2 fused; 512-thread block = 8 waves per 16-node tile.
// Stage: wave wv, rows 2wv/2wv+1 -- lanes 0..deg-1 gather slot->aggS,d5 in
// PARALLEL (one depth-2 chain per row) into LDS. Wave-private: no barrier.
// Compute: lane = channel; per edge m = dot4(stA,W1col) + b1c*stQ (LDS
// broadcast reads); acc += relu(m); self-loop = edge s=d; acc *= d5[d].
// Then bf16 tile -> 2x mfma 16x16x32 (waves 0-3), layouts verified r3-r9.
__global__ __launch_bounds__(512) void k_l2(Args a) {
    __shared__ float4 stA[16][CAP];          // 16 KB: staged aggS rows
    __shared__ float4 stQ4[16][CAP / 4];     // 4 KB: staged d5, float4-packed
    __shared__ __hip_bfloat16 tile[16][72];  // 2.3 KB
    int tid = threadIdx.x;
    int wv = tid >> 6, lane = tid & 63;
    int base = blockIdx.x * 16;

    int degR[2];
    // ---- stage (lane-parallel gather, wave-private rows) ----
#pragma unroll
    for (int rr = 0; rr < 2; ++rr) {
        int row = wv * 2 + rr;
        int node = base + row;
        degR[rr] = 0;
        if (node < NN) {
            int deg = a.cursor[node];
            degR[rr] = deg;
            const unsigned short* sl = a.slots + node * CAP;
            if (lane < deg) {
                int s = sl[lane];
                stA[row][lane] = a.aggS[s];
                reinterpret_cast<float*>(&stQ4[row][0])[lane] = a.d5[s];
            }
        }
    }

    // ---- compute (per-channel sweep from LDS) ----
    float w0 = a.W1[lane], w1 = a.W1[64 + lane];
    float w2 = a.W1[128 + lane], w3 = a.W1[192 + lane];
    float b1c = a.b1[lane];
#pragma unroll
    for (int rr = 0; rr < 2; ++rr) {
        int row = wv * 2 + rr;
        int node = base + row;
        float acc = 0.f;
        if (node < NN) {
            int deg = degR[rr];
            float4 as = a.aggS[node];
            float dn = a.d5[node];
            float ms = fmaf(as.x, w0, fmaf(as.y, w1,
                        fmaf(as.z, w2, fmaf(as.w, w3, b1c * dn))));
            acc = fmaxf(ms, 0.f);  // self-loop message
            int j = 0;
            for (; j + 3 < deg; j += 4) {
                float4 q4 = stQ4[row][j >> 2];
                float4 e0 = stA[row][j],     e1 = stA[row][j + 1];
                float4 e2 = stA[row][j + 2], e3 = stA[row][j + 3];
                float m0 = fmaf(e0.x, w0, fmaf(e0.y, w1, fmaf(e0.z, w2, fmaf(e0.w, w3, b1c * q4.x))));
                float m1 = fmaf(e1.x, w0, fmaf(e1.y, w1, fmaf(e1.z, w2, fmaf(e1.w, w3, b1c * q4.y))));
                float m2 = fmaf(e2.x, w0, fmaf(e2.y, w1, fmaf(e2.z, w2, fmaf(e2.w, w3, b1c * q4.z))));
                float m3 = fmaf(e3.x, w0, fmaf(e3.y, w1, fmaf(e3.z, w2, fmaf(e3.w, w3, b1c * q4.w))));
                acc += fmaxf(m0, 0.f);
                acc += fmaxf(m1, 0.f);
                acc += fmaxf(m2, 0.f);
                acc += fmaxf(m3, 0.f);
            }
            for (; j < deg; ++j) {
                float4 e0 = stA[row][j];
                float q = reinterpret_cast<const float*>(&stQ4[row][0])[j];
                float m0 = fmaf(e0.x, w0, fmaf(e0.y, w1,
                            fmaf(e0.z, w2, fmaf(e0.w, w3, b1c * q))));
                acc += fmaxf(m0, 0.f);
            }
            acc *= dn;
        }
        tile[row][lane] = __float2bfloat16(acc);
    }
    __syncthreads();

    // ---- MFMA epilogue (waves 0-3; fragment layouts verified r3-r9) ----
    if (wv < 4) {
        int g = lane >> 4, c16 = lane & 15;
        int col = wv * 16 + c16;
        bf16x8 a0 = *reinterpret_cast<const bf16x8*>(&tile[c16][g * 8]);
        bf16x8 a1 = *reinterpret_cast<const bf16x8*>(&tile[c16][32 + g * 8]);
        bf16x8 bb0 = *reinterpret_cast<const bf16x8*>(a.w2t + col * 64 + g * 8);
        bf16x8 bb1 = *reinterpret_cast<const bf16x8*>(a.w2t + col * 64 + 32 + g * 8);
        f32x4 acc4 = {0.f, 0.f, 0.f, 0.f};
        acc4 = __builtin_amdgcn_mfma_f32_16x16x32_bf16(a0, bb0, acc4, 0, 0, 0);
        acc4 = __builtin_amdgcn_mfma_f32_16x16x32_bf16(a1, bb1, acc4, 0, 0, 0);
        float b2v = a.b2[col];
#pragma unroll
        for (int rg = 0; rg < 4; ++rg) {
            int node = base + g * 4 + rg;
            if (node < NN) a.out[node * 64 + col] = fmaxf(acc4[rg] + b2v, 0.f);
        }
    }
}

extern "C" void kernel_launch(void* const* d_in, const int* in_sizes, int n_in,
                              void* d_out, int out_size, void* d_ws, size_t ws_size,
                              hipStream_t stream) {
    const float* x  = (const float*)d_in[0];
    const int*   ei = (const int*)d_in[1];  // [2, NE]: src row then dst row
    const float* W1 = (const float*)d_in[2];
    const float* b1 = (const float*)d_in[3];
    const float* W2 = (const float*)d_in[4];
    const float* b2 = (const float*)d_in[5];

    char* w = (char*)d_ws;
    auto take = [&](size_t bytes) { char* p = w; w += ALIGN_UP(bytes, 256); return p; };
    int*            cursor = (int*)           take((size_t)NN * 4);
    unsigned short* slots  = (unsigned short*)take((size_t)NN * CAP * 2);  // 6.4 MB
    float*          aggS   = (float*)         take((size_t)NN * 16);
    float*          d5     = (float*)         take((size_t)NN * 4);
    __hip_bfloat16* w2t    = (__hip_bfloat16*)take(4096 * 2);

    Args args;
    args.x = (const float4*)x;
    args.src2 = (const int2*)ei;
    args.dst2 = (const int2*)(ei + NE);
    args.W1 = W1; args.b1 = b1; args.W2 = W2; args.b2 = b2;
    args.cursor = cursor; args.slots = slots;
    args.aggS = (float4*)aggS; args.d5 = d5; args.w2t = w2t;
    args.out = (float*)d_out;

    hipMemsetAsync(cursor, 0, (size_t)NN * 4, stream);
    k_fill<<<(NE / 2 + 255) / 256, 256, 0, stream>>>(args);  // 1563 blocks
    k_agg<<<NN / 16, 256, 0, stream>>>(args);                // 3125 blocks
    k_l2<<<NB_TILE, 512, 0, stream>>>(args);                 // 3128 blocks
}

// Round 11
// 120.670 us; speedup vs baseline: 1.4766x; 1.2533x over previous
//
#include <hip/hip_runtime.h>
#include <hip/hip_bf16.h>

// 2-layer GCN on MI355X, round 11.
// r9/r10 lessons: global ATOMICS are the fill's cost (~14G/s ceiling,
// occupancy/payload-insensitive); plain L2-local stores are cheap. So the
// bucket build becomes two passes with only ~38K atomics (one per block,bin):
//   memset(bincur) -> k_bin (coarse-bin edges, LDS histogram + extent
//   reservation + plain packed stores) -> k_bucket (per-bin fine histogram ->
//   deg/d5/xd coalesced; LDS-cursor placement into slots, L2-local stores)
//   -> k_agg (aggS from xd) -> k_l2 (r10's LDS-staged gather + MFMA).

constexpr int NN = 50000;
constexpr int NE = 800000;
constexpr int CAP = 64;        // slot capacity; in-deg ~ Poisson(16), P(>=65) ~ 1e-15
constexpr int NBIN = 196;      // coarse bins of 256 dsts (bin = d >> 8)
constexpr int BINCAP = 4608;   // mean 4096, sd ~64 -> 8 sigma headroom
constexpr int NB_TILE = 3128;  // ceil(50000/16)

typedef __attribute__((ext_vector_type(8))) short bf16x8;
typedef __attribute__((ext_vector_type(4))) float f32x4;

#define ALIGN_UP(x, a) (((x) + (a) - 1) / (a) * (a))

struct Args {
    const float4* x;
    const int4* src4;
    const int4* dst4;
    const float* W1;
    const float* b1;
    const float* W2;
    const float* b2;
    int* bincur;             // [NBIN] extent cursors (memset to 0)
    unsigned int* binned;    // [NBIN * BINCAP] packed (dlocal<<16)|src
    int* deg;                // [NN]
    unsigned short* slots;   // [NN * CAP] src ids (16-bit)
    float4* xd;              // x[n] * dinv[n]
    float4* aggS;            // (A_hat x)[n] * dinv[n]
    float* d5;               // dinv[n]
    __hip_bfloat16* w2t;     // w2t[c][k] = bf16(W2[k][c])
    float* out;
};

// Pass 1: coarse-bin the edge list. 512 thr x 8 edges = 4096 edges/block.
// LDS histogram over bins; ONE global atomic per (block,bin) reserves an
// extent; placement via LDS cursors + plain stores. Block 0 also builds w2t.
__global__ __launch_bounds__(512) void k_bin(Args a) {
    __shared__ int hist[256];
    __shared__ int lcur[256];  // global write cursor per bin for this block
    int t = threadIdx.x, blk = blockIdx.x;
    if (t < 256) hist[t] = 0;
    __syncthreads();

    int4 s[2], d[2];
    bool v[2];
#pragma unroll
    for (int r = 0; r < 2; ++r) {
        int idx4 = blk * 1024 + r * 512 + t;
        v[r] = idx4 < NE / 4;
        if (v[r]) { s[r] = a.src4[idx4]; d[r] = a.dst4[idx4]; }
    }
#pragma unroll
    for (int r = 0; r < 2; ++r) if (v[r]) {
        atomicAdd(&hist[d[r].x >> 8], 1);
        atomicAdd(&hist[d[r].y >> 8], 1);
        atomicAdd(&hist[d[r].z >> 8], 1);
        atomicAdd(&hist[d[r].w >> 8], 1);
    }
    __syncthreads();
    if (t < NBIN) {
        int h = hist[t];
        int base = h ? atomicAdd(&a.bincur[t], h) : 0;
        lcur[t] = t * BINCAP + base;
    }
    __syncthreads();
#pragma unroll
    for (int r = 0; r < 2; ++r) if (v[r]) {
        int b0 = d[r].x >> 8, p0 = atomicAdd(&lcur[b0], 1);
        if (p0 < (b0 + 1) * BINCAP) a.binned[p0] = ((unsigned)(d[r].x & 255) << 16) | (unsigned)s[r].x;
        int b1 = d[r].y >> 8, p1 = atomicAdd(&lcur[b1], 1);
        if (p1 < (b1 + 1) * BINCAP) a.binned[p1] = ((unsigned)(d[r].y & 255) << 16) | (unsigned)s[r].y;
        int b2 = d[r].z >> 8, p2 = atomicAdd(&lcur[b2], 1);
        if (p2 < (b2 + 1) * BINCAP) a.binned[p2] = ((unsigned)(d[r].z & 255) << 16) | (unsigned)s[r].z;
        int b3 = d[r].w >> 8, p3 = atomicAdd(&lcur[b3], 1);
        if (p3 < (b3 + 1) * BINCAP) a.binned[p3] = ((unsigned)(d[r].w & 255) << 16) | (unsigned)s[r].w;
    }

    if (blk == 0) {
        for (int idx = t; idx < 4096; idx += 512) {
            int c = idx >> 6, k = idx & 63;
            a.w2t[idx] = __float2bfloat16(a.W2[k * 64 + c]);
        }
    }
}

// Pass 2: one block per bin. Fine histogram (LDS) -> deg/d5/xd coalesced;
// then LDS-cursor placement of srcs into slots (32KB L2-local region/block).
__global__ __launch_bounds__(512) void k_bucket(Args a) {
    __shared__ int h[256], cur[256];
    int t = threadIdx.x, b = blockIdx.x;
    if (t < 256) { h[t] = 0; cur[t] = 0; }
    __syncthreads();
    int cnt = a.bincur[b];
    if (cnt > BINCAP) cnt = BINCAP;
    const unsigned int* src = a.binned + b * BINCAP;
    for (int i = t; i < cnt; i += 512) atomicAdd(&h[src[i] >> 16], 1);
    __syncthreads();
    if (t < 256) {
        int d = (b << 8) + t;
        if (d < NN) {
            int dg = h[t];
            float di = rsqrtf((float)(dg + 1));
            a.deg[d] = dg < CAP ? dg : CAP;
            a.d5[d] = di;
            float4 xs = a.x[d];
            a.xd[d] = make_float4(xs.x * di, xs.y * di, xs.z * di, xs.w * di);
        }
    }
    __syncthreads();
    for (int i = t; i < cnt; i += 512) {
        unsigned int e = src[i];
        int dl = e >> 16;
        int pos = atomicAdd(&cur[dl], 1);   // LDS atomic
        if (pos < CAP)
            a.slots[(((b << 8) + dl) * CAP) + pos] = (unsigned short)(e & 0xFFFF);
    }
}

// aggS[n] = (x[n]*di^2 + di * sum_s x[s]*dinv[s]) * di = x[n]*di^3 + di^2*sum(xd[s]).
// 16 lanes per node, 4 nodes per wave.
__global__ __launch_bounds__(256) void k_agg(Args a) {
    int tid = threadIdx.x;
    int t = tid & 15;
    int node = (blockIdx.x * 256 + tid) >> 4;  // grid exact: NN/16 blocks
    int deg = a.deg[node];
    float ax = 0.f, ay = 0.f, az = 0.f, aw = 0.f;
    const unsigned short* sl = a.slots + node * CAP;
    for (int j = t; j < deg; j += 16) {
        float4 xs = a.xd[sl[j]];
        ax += xs.x; ay += xs.y; az += xs.z; aw += xs.w;
    }
#pragma unroll
    for (int o = 8; o >= 1; o >>= 1) {
        ax += __shfl_xor(ax, o);
        ay += __shfl_xor(ay, o);
        az += __shfl_xor(az, o);
        aw += __shfl_xor(aw, o);
    }
    if (t == 0) {
        float di = a.d5[node];
        float di2 = di * di, di3 = di2 * di;
        float4 xs = a.x[node];
        a.aggS[node] = make_float4(fmaf(ax, di2, xs.x * di3),
                                   fmaf(ay, di2, xs.y * di3),
                                   fmaf(az, di2, xs.z * di3),
                                   fmaf(aw, di2, xs.w * di3));
    }
}

// Layer 2 fused (r10 structure, verified): 512-thr block = 8 waves per
// 16-node tile. Stage: lane-parallel gather of slot->aggS,d5 into LDS
// (wave-private, no barrier). Compute: per-channel sweep from LDS;
// m = dot4(stA, W1col) + b1c*stQ; acc += relu(m); self-loop = edge s=d;
// acc *= d5[d]. Then bf16 tile -> 2x mfma 16x16x32 (waves 0-3).
__global__ __launch_bounds__(512) void k_l2(Args a) {
    __shared__ float4 stA[16][CAP];          // 16 KB
    __shared__ float4 stQ4[16][CAP / 4];     // 4 KB
    __shared__ __hip_bfloat16 tile[16][72];  // 2.3 KB
    int tid = threadIdx.x;
    int wv = tid >> 6, lane = tid & 63;
    int base = blockIdx.x * 16;

    int degR[2];
#pragma unroll
    for (int rr = 0; rr < 2; ++rr) {
        int row = wv * 2 + rr;
        int node = base + row;
        degR[rr] = 0;
        if (node < NN) {
            int deg = a.deg[node];
            degR[rr] = deg;
            const unsigned short* sl = a.slots + node * CAP;
            if (lane < deg) {
                int s = sl[lane];
                stA[row][lane] = a.aggS[s];
                reinterpret_cast<float*>(&stQ4[row][0])[lane] = a.d5[s];
            }
        }
    }

    float w0 = a.W1[lane], w1 = a.W1[64 + lane];
    float w2 = a.W1[128 + lane], w3 = a.W1[192 + lane];
    float b1c = a.b1[lane];
#pragma unroll
    for (int rr = 0; rr < 2; ++rr) {
        int row = wv * 2 + rr;
        int node = base + row;
        float acc = 0.f;
        if (node < NN) {
            int deg = degR[rr];
            float4 as = a.aggS[node];
            float dn = a.d5[node];
            float ms = fmaf(as.x, w0, fmaf(as.y, w1,
                        fmaf(as.z, w2, fmaf(as.w, w3, b1c * dn))));
            acc = fmaxf(ms, 0.f);  // self-loop message
            int j = 0;
            for (; j + 3 < deg; j += 4) {
                float4 q4 = stQ4[row][j >> 2];
                float4 e0 = stA[row][j],     e1 = stA[row][j + 1];
                float4 e2 = stA[row][j + 2], e3 = stA[row][j + 3];
                float m0 = fmaf(e0.x, w0, fmaf(e0.y, w1, fmaf(e0.z, w2, fmaf(e0.w, w3, b1c * q4.x))));
                float m1 = fmaf(e1.x, w0, fmaf(e1.y, w1, fmaf(e1.z, w2, fmaf(e1.w, w3, b1c * q4.y))));
                float m2 = fmaf(e2.x, w0, fmaf(e2.y, w1, fmaf(e2.z, w2, fmaf(e2.w, w3, b1c * q4.z))));
                float m3 = fmaf(e3.x, w0, fmaf(e3.y, w1, fmaf(e3.z, w2, fmaf(e3.w, w3, b1c * q4.w))));
                acc += fmaxf(m0, 0.f);
                acc += fmaxf(m1, 0.f);
                acc += fmaxf(m2, 0.f);
                acc += fmaxf(m3, 0.f);
            }
            for (; j < deg; ++j) {
                float4 e0 = stA[row][j];
                float q = reinterpret_cast<const float*>(&stQ4[row][0])[j];
                float m0 = fmaf(e0.x, w0, fmaf(e0.y, w1,
                            fmaf(e0.z, w2, fmaf(e0.w, w3, b1c * q))));
                acc += fmaxf(m0, 0.f);
            }
            acc *= dn;
        }
        tile[row][lane] = __float2bfloat16(acc);
    }
    __syncthreads();

    if (wv < 4) {
        int g = lane >> 4, c16 = lane & 15;
        int col = wv * 16 + c16;
        bf16x8 a0 = *reinterpret_cast<const bf16x8*>(&tile[c16][g * 8]);
        bf16x8 a1 = *reinterpret_cast<const bf16x8*>(&tile[c16][32 + g * 8]);
        bf16x8 bb0 = *reinterpret_cast<const bf16x8*>(a.w2t + col * 64 + g * 8);
        bf16x8 bb1 = *reinterpret_cast<const bf16x8*>(a.w2t + col * 64 + 32 + g * 8);
        f32x4 acc4 = {0.f, 0.f, 0.f, 0.f};
        acc4 = __builtin_amdgcn_mfma_f32_16x16x32_bf16(a0, bb0, acc4, 0, 0, 0);
        acc4 = __builtin_amdgcn_mfma_f32_16x16x32_bf16(a1, bb1, acc4, 0, 0, 0);
        float b2v = a.b2[col];
#pragma unroll
        for (int rg = 0; rg < 4; ++rg) {
            int node = base + g * 4 + rg;
            if (node < NN) a.out[node * 64 + col] = fmaxf(acc4[rg] + b2v, 0.f);
        }
    }
}

extern "C" void kernel_launch(void* const* d_in, const int* in_sizes, int n_in,
                              void* d_out, int out_size, void* d_ws, size_t ws_size,
                              hipStream_t stream) {
    const float* x  = (const float*)d_in[0];
    const int*   ei = (const int*)d_in[1];  // [2, NE]: src row then dst row
    const float* W1 = (const float*)d_in[2];
    const float* b1 = (const float*)d_in[3];
    const float* W2 = (const float*)d_in[4];
    const float* b2 = (const float*)d_in[5];

    char* w = (char*)d_ws;
    auto take = [&](size_t bytes) { char* p = w; w += ALIGN_UP(bytes, 256); return p; };
    int*            bincur = (int*)           take((size_t)NBIN * 4);
    unsigned int*   binned = (unsigned int*)  take((size_t)NBIN * BINCAP * 4);  // 3.6 MB
    int*            deg    = (int*)           take((size_t)NN * 4);
    unsigned short* slots  = (unsigned short*)take((size_t)NN * CAP * 2);       // 6.4 MB
    float*          xd     = (float*)         take((size_t)NN * 16);
    float*          aggS   = (float*)         take((size_t)NN * 16);
    float*          d5     = (float*)         take((size_t)NN * 4);
    __hip_bfloat16* w2t    = (__hip_bfloat16*)take(4096 * 2);

    Args args;
    args.x = (const float4*)x;
    args.src4 = (const int4*)ei;
    args.dst4 = (const int4*)(ei + NE);
    args.W1 = W1; args.b1 = b1; args.W2 = W2; args.b2 = b2;
    args.bincur = bincur; args.binned = binned; args.deg = deg;
    args.slots = slots; args.xd = (float4*)xd;
    args.aggS = (float4*)aggS; args.d5 = d5; args.w2t = w2t;
    args.out = (float*)d_out;

    hipMemsetAsync(bincur, 0, (size_t)NBIN * 4, stream);
    k_bin<<<(NE / 4 + 1023) / 1024, 512, 0, stream>>>(args);   // 196 blocks
    k_bucket<<<NBIN, 512, 0, stream>>>(args);                  // 196 blocks
    k_agg<<<NN / 16, 256, 0, stream>>>(args);                  // 3125 blocks
    k_l2<<<NB_TILE, 512, 0, stream>>>(args);                   // 3128 blocks
}